// Round 8
// baseline (92.194 us; speedup 1.0000x reference)
//
#include <hip/hip_runtime.h>
#include <hip/hip_bf16.h>

#define CIN  64
#define HH   128
#define WW   128
#define COUT 128
#define HO   126
#define WO   126
#define NB   32
#define HW   (HH * WW)

typedef __bf16 bf16x8 __attribute__((ext_vector_type(8)));
typedef float f32x16 __attribute__((ext_vector_type(16)));

// ws granule layout: [s(9)][g8(8)][cout(128)] 16B granules
// granule(s,g8,cout)[j] = bf16(w[cout][ci = 8*g8 + j][s])
__global__ void wreorder_3556(const float* __restrict__ w, unsigned short* __restrict__ ws2) {
    int e = blockIdx.x * 256 + threadIdx.x;      // 0..73727
    if (e >= 73728) return;
    int j = e & 7, cout = (e >> 3) & 127, g8 = (e >> 10) & 7, s = e >> 13;
    __bf16 v = (__bf16)w[cout * 576 + (g8 * 8 + j) * 9 + s];
    ws2[e] = __builtin_bit_cast(unsigned short, v);
}

// LDS: xs [row(3)][cg(8)][col(128)] 16B granules (ci-major) @0 = 48KB | pmin[4][128] @49152
#define XS_OFF  0
#define PM_OFF  49152
#define SMEM_BYTES (49152 + 4 * 128 * 4)   // 51200 -> 3 blocks/CU

template<bool USE_WS>
__global__ __launch_bounds__(512, 6)
void conv_min_tanh_3556(const float* __restrict__ x, const float* __restrict__ w,
                        const float* __restrict__ bias,
                        const unsigned char* __restrict__ wsr_b,
                        float* __restrict__ out) {
    __shared__ __align__(16) unsigned char smem[SMEM_BYTES];
    float* pmin = (float*)(smem + PM_OFF);

    // XCD-chunked bijective swizzle (4032 % 8 == 0)
    const int bid = blockIdx.x;
    const int blk = (bid & 7) * (NB * HO / 8) + (bid >> 3);
    const int b  = blk / HO;
    const int ho = blk - b * HO;

    const int tid  = threadIdx.x;
    const int lane = tid & 63;
    const int wid  = tid >> 6;          // 0..7
    const int l31 = lane & 31;
    const int l5  = lane >> 5;
    const int waveM = wid >> 1;         // 0..3
    const int mb  = waveM * 32;         // cout base
    const int cb  = (wid & 1) * 64;     // col base

    // ---- stage x into xs[row][cg][col] granules (each granule = 8 ci for one col)
    // thread (cg = tid>>6, c0 = tid&63) covers rows 0..2, cols {c0, c0+64}
    {
        const int cg = tid >> 6, c0 = tid & 63;
        const float* xb = x + (size_t)b * CIN * HW + (size_t)(cg * 8) * HW + (size_t)ho * WW;
        #pragma unroll
        for (int row = 0; row < 3; ++row) {
            #pragma unroll
            for (int i = 0; i < 2; ++i) {
                const int col = c0 + i * 64;
                union { unsigned short us[8]; int4 i4; } p;
                #pragma unroll
                for (int j = 0; j < 8; ++j) {
                    __bf16 t = (__bf16)xb[(size_t)j * HW + (size_t)row * WW + col];
                    p.us[j] = __builtin_bit_cast(unsigned short, t);
                }
                *(int4*)(smem + XS_OFF + (((row * 8 + cg) * 128) + col) * 16) = p.i4;
            }
        }
    }
    __syncthreads();

    // ---- B read bases: addr = kh*16384 + ks*4096 + baseB[nt][kw]   (stride-16B: conflict-free)
    // NOTE: cols 128,129 read out-of-tile (pmin region, in-bounds of smem) -> only pollute
    // discarded output cols 126,127; garbage is column-local in MFMA.
    int baseB[2][3];
    #pragma unroll
    for (int nt = 0; nt < 2; ++nt)
        #pragma unroll
        for (int kw = 0; kw < 3; ++kw)
            baseB[nt][kw] = XS_OFF + (cb + nt * 32 + l31 + kw) * 16 + l5 * 2048;

    // ---- A stream base: granule(s, g8 = 2ks+l5, cout = mb+l31); addr = s*16384 + ks*4096
    const unsigned char* wA = USE_WS ? (wsr_b + l5 * 2048 + (size_t)(mb + l31) * 16) : nullptr;

    f32x16 acc[2] = {};

    #pragma unroll
    for (int s = 0; s < 9; ++s) {
        const int kh = s / 3, kw = s % 3;          // compile-time after unroll
        const int khOff = kh * 16384;

        bf16x8 A[4], B[4][2];
        #pragma unroll
        for (int ks = 0; ks < 4; ++ks) {
            if constexpr (USE_WS) {
                A[ks] = *(const bf16x8*)(wA + s * 16384 + ks * 4096);
            } else {
                #pragma unroll
                for (int j = 0; j < 8; ++j)
                    A[ks][j] = (__bf16)w[(mb + l31) * 576 +
                                         ((2 * ks + l5) * 8 + j) * 9 + s];
            }
            B[ks][0] = *(const bf16x8*)(smem + khOff + ks * 4096 + baseB[0][kw]);
            B[ks][1] = *(const bf16x8*)(smem + khOff + ks * 4096 + baseB[1][kw]);
        }
        #pragma unroll
        for (int ks = 0; ks < 4; ++ks) {
            acc[0] = __builtin_amdgcn_mfma_f32_32x32x16_bf16(A[ks], B[ks][0], acc[0], 0, 0, 0);
            acc[1] = __builtin_amdgcn_mfma_f32_32x32x16_bf16(A[ks], B[ks][1], acc[1], 0, 0, 0);
        }
    }

    // ---- epilogue: +bias, min over this wave's 32 couts, cross-lane, cross-wave
    float pm[2] = {1e30f, 1e30f};
    #pragma unroll
    for (int r = 0; r < 16; ++r) {
        float bv = bias[mb + (r & 3) + 8 * (r >> 2) + 4 * l5];
        pm[0] = fminf(pm[0], acc[0][r] + bv);
        pm[1] = fminf(pm[1], acc[1][r] + bv);
    }
    pm[0] = fminf(pm[0], __shfl_xor(pm[0], 32, 64));
    pm[1] = fminf(pm[1], __shfl_xor(pm[1], 32, 64));
    if (l5 == 0) {
        pmin[waveM * 128 + cb + l31]      = pm[0];
        pmin[waveM * 128 + cb + 32 + l31] = pm[1];
    }
    __syncthreads();
    if (tid < WO) {
        float v = fminf(fminf(pmin[tid], pmin[128 + tid]),
                        fminf(pmin[256 + tid], pmin[384 + tid]));
        v = tanhf(tanhf(v));
        out[((size_t)b * HO + ho) * WO + tid] = v;
    }
}

extern "C" void kernel_launch(void* const* d_in, const int* in_sizes, int n_in,
                              void* d_out, int out_size, void* d_ws, size_t ws_size,
                              hipStream_t stream) {
    const float* x    = (const float*)d_in[0];
    const float* w    = (const float*)d_in[1];
    const float* bias = (const float*)d_in[2];
    float* out = (float*)d_out;

    const size_t ws_needed = (size_t)9 * 8 * 128 * 16;   // 147456 B
    if (ws_size >= ws_needed) {
        unsigned short* wsb = (unsigned short*)d_ws;
        wreorder_3556<<<288, 256, 0, stream>>>(w, wsb);
        conv_min_tanh_3556<true><<<NB * HO, 512, 0, stream>>>(x, w, bias, (const unsigned char*)wsb, out);
    } else {
        conv_min_tanh_3556<false><<<NB * HO, 512, 0, stream>>>(x, w, bias, nullptr, out);
    }
}